// Round 1
// baseline (3822.357 us; speedup 1.0000x reference)
//
#include <hip/hip_runtime.h>
#include <math.h>

#define CIN 256
#define HIN 38
#define WIN 38
#define NFRAMES 300
#define COUT1 128
#define P1 1521      // 39*39
#define PSTR 1524    // padded spatial stride (multiple of 4 for float4 stores)
#define HW2 1444     // 38*38
#define NSC 5776     // 4*38*38
#define CHUNK 75
#define NCHUNKS 4

// ---------------- weight repack kernels ----------------
// W1r[k][co], k = kid*256 + ci  (kid = kh*2+kw)
__global__ void repack_w1(const float* __restrict__ W1, float* __restrict__ W1r) {
    int e = blockIdx.x * 256 + threadIdx.x;          // < 131072
    int co = e & 127;
    int k  = e >> 7;
    int kid = k >> 8, ci = k & 255;
    W1r[e] = W1[((co * 256) + ci) * 4 + kid];
}

// Wl[((ci4*4+kid)*24 + ch)*4 + j], ci = ci4*4+j ; ch<8 -> Wc, else Wb
__global__ void repack_wl(const float* __restrict__ Wc, const float* __restrict__ Wb,
                          float* __restrict__ Wl) {
    int e = blockIdx.x * 256 + threadIdx.x;          // < 12288
    int j = e & 3;
    int r = e >> 2;
    int ch = r % 24;
    int q  = r / 24;         // ci4*4+kid
    int kid = q & 3, ci4 = q >> 2;
    int ci = ci4 * 4 + j;
    float v = (ch < 8) ? Wc[(ch * 128 + ci) * 4 + kid]
                       : Wb[((ch - 8) * 128 + ci) * 4 + kid];
    Wl[e] = v;
}

// ---------------- conv1: 2x2 pad=1 conv + bias + relu ----------------
// per-frame GEMM: C[128][1521] = W1r[1024][128]^T * im2col[1024][1521]
// grid (12 pixel tiles, 1, CHUNK frames), block 256, BM=BN=128, BK=16, 8x8/thread
__global__ __launch_bounds__(256) void conv1_kernel(
    const float* __restrict__ bf, const float* __restrict__ W1r,
    const float* __restrict__ b1, float* __restrict__ xout, int frame0)
{
    __shared__ __align__(16) float As[16][128];
    __shared__ __align__(16) float Bs[16][128];
    const int tid = threadIdx.x;
    const int tx = tid & 15, ty = tid >> 4;
    const int fz = blockIdx.z;
    const int b  = frame0 + fz;
    const int p0 = blockIdx.x * 128;
    const float* bfb = bf + (size_t)b * (CIN * HIN * WIN);

    // precompute per-thread staging coords (invariant over K loop)
    int  s_h[8], s_w[8];
    bool s_ok[8];
#pragma unroll
    for (int it = 0; it < 8; ++it) {
        int e = it * 256 + tid;
        int n = e & 127;
        int p = p0 + n;
        bool ok = p < P1;
        int pp = ok ? p : 0;
        int hq = pp / 39;
        int wq = pp - hq * 39;
        s_h[it] = hq; s_w[it] = wq; s_ok[it] = ok;
    }

    float acc[8][8];
#pragma unroll
    for (int i = 0; i < 8; ++i)
#pragma unroll
        for (int j = 0; j < 8; ++j) acc[i][j] = 0.f;

    for (int k0 = 0; k0 < 1024; k0 += 16) {
        // stage A tile (W1r): 16x128 floats, 2 float4 per thread
#pragma unroll
        for (int it = 0; it < 2; ++it) {
            int f = it * 256 + tid;
            int k = f >> 5, m4 = (f & 31) << 2;
            *(float4*)&As[k][m4] = *(const float4*)&W1r[(size_t)(k0 + k) * 128 + m4];
        }
        // stage B tile (im2col): 16x128, 8 scalars per thread (coalesced rows)
#pragma unroll
        for (int it = 0; it < 8; ++it) {
            int e = it * 256 + tid;
            int k = e >> 7, n = e & 127;
            int kg = k0 + k;
            int kid = kg >> 8, ci = kg & 255;
            int hi = s_h[it] + (kid >> 1) - 1;
            int wi = s_w[it] + (kid & 1) - 1;
            float v = 0.f;
            if (s_ok[it] && (unsigned)hi < 38u && (unsigned)wi < 38u)
                v = bfb[(ci * 38 + hi) * 38 + wi];
            Bs[k][n] = v;
        }
        __syncthreads();
#pragma unroll
        for (int k = 0; k < 16; ++k) {
            float4 a0  = *(const float4*)&As[k][ty * 4];
            float4 a1  = *(const float4*)&As[k][ty * 4 + 64];
            float4 b0  = *(const float4*)&Bs[k][tx * 4];
            float4 b1v = *(const float4*)&Bs[k][tx * 4 + 64];
            float av[8] = {a0.x, a0.y, a0.z, a0.w, a1.x, a1.y, a1.z, a1.w};
            float bv[8] = {b0.x, b0.y, b0.z, b0.w, b1v.x, b1v.y, b1v.z, b1v.w};
#pragma unroll
            for (int i = 0; i < 8; ++i)
#pragma unroll
                for (int j = 0; j < 8; ++j)
                    acc[i][j] = fmaf(av[i], bv[j], acc[i][j]);
        }
        __syncthreads();
    }

    // epilogue: bias + relu, float4 stores into padded x
#pragma unroll
    for (int ih = 0; ih < 2; ++ih)
#pragma unroll
        for (int ii = 0; ii < 4; ++ii) {
            int m = ih * 64 + ty * 4 + ii;
            float bias = b1[m];
            float* orow = xout + ((size_t)fz * COUT1 + m) * PSTR;
#pragma unroll
            for (int jh = 0; jh < 2; ++jh) {
                int p = p0 + jh * 64 + tx * 4;
                if (p < P1) {
                    float4 r;
                    r.x = fmaxf(acc[ih * 4 + ii][jh * 4 + 0] + bias, 0.f);
                    r.y = fmaxf(acc[ih * 4 + ii][jh * 4 + 1] + bias, 0.f);
                    r.z = fmaxf(acc[ih * 4 + ii][jh * 4 + 2] + bias, 0.f);
                    r.w = fmaxf(acc[ih * 4 + ii][jh * 4 + 3] + bias, 0.f);
                    *(float4*)&orow[p] = r;
                }
            }
        }
}

// ---------------- stage2: cls + deltas + scores ----------------
// block = (row-pair h0=2*bx, frame). xs stages 3 x-rows; thread = (w, chgroup of 4)
__global__ __launch_bounds__(256) void stage2_kernel(
    const float* __restrict__ x, const float* __restrict__ Wl,
    const float* __restrict__ bcv, const float* __restrict__ bbv,
    float* __restrict__ scores, float* __restrict__ deltas, int frame0)
{
    __shared__ __align__(16) float xs[3][39][132];
    __shared__ float clsrow[2][8][38];
    const int tid = threadIdx.x;
    const int h0 = blockIdx.x * 2;
    const int fz = blockIdx.y;
    const int b  = frame0 + fz;
    const float* xb = x + (size_t)fz * COUT1 * PSTR;

    // stage x rows h0..h0+2 (transposed to channel-contiguous)
    for (int e = tid; e < 128 * 117; e += 256) {
        int ci = e / 117, off = e - ci * 117;   // off = r*39 + pix
        ((float*)xs)[off * 132 + ci] = xb[ci * PSTR + h0 * 39 + off];
    }
    __syncthreads();

    int w = 0, chg = 0;
    const bool active = tid < 228;              // 38 pixels x 6 ch-groups
    if (active) { w = tid / 6; chg = tid - w * 6; }

    float acc[2][4];
#pragma unroll
    for (int r = 0; r < 2; ++r)
#pragma unroll
        for (int cc = 0; cc < 4; ++cc) {
            int ch = chg * 4 + cc;
            acc[r][cc] = (ch < 8) ? bcv[ch] : bbv[ch - 8];
        }

    for (int ci4 = 0; ci4 < 32; ++ci4) {
#pragma unroll
        for (int kid = 0; kid < 4; ++kid) {
            int kh = kid >> 1, kw = kid & 1;
            float4 x0 = *(const float4*)&xs[kh][w + kw][ci4 * 4];
            float4 x1 = *(const float4*)&xs[kh + 1][w + kw][ci4 * 4];
#pragma unroll
            for (int cc = 0; cc < 4; ++cc) {
                float4 wv = *(const float4*)&Wl[(((ci4 * 4 + kid) * 24) + chg * 4 + cc) * 4];
                acc[0][cc] += x0.x * wv.x + x0.y * wv.y + x0.z * wv.z + x0.w * wv.w;
                acc[1][cc] += x1.x * wv.x + x1.y * wv.y + x1.z * wv.z + x1.w * wv.w;
            }
        }
    }

    if (active) {
#pragma unroll
        for (int r = 0; r < 2; ++r) {
            int h = h0 + r;
#pragma unroll
            for (int cc = 0; cc < 4; ++cc) {
                int ch = chg * 4 + cc;
                if (ch < 8) clsrow[r][ch][w] = acc[r][cc];
                else deltas[((size_t)b * 16 + (ch - 8)) * HW2 + h * 38 + w] = acc[r][cc];
            }
        }
    }
    __syncthreads();

    // softmax-pair -> scores, layout i = a*1444 + h*38 + w
    for (int e = tid; e < 304; e += 256) {
        int r = e / 152, t2 = e - r * 152;
        int a = t2 & 3, w2 = t2 >> 2;
        float z1 = clsrow[r][a][w2];
        float z2 = clsrow[r][a + 4][w2];
        float mx = fmaxf(z1, z2);
        float e1 = expf(z1 - mx), e2 = expf(z2 - mx);
        scores[(size_t)b * NSC + a * HW2 + (h0 + r) * 38 + w2] = e2 / (e1 + e2);
    }
}

// ---------------- per-frame argmax + box decode ----------------
__global__ __launch_bounds__(256) void argmax_kernel(
    const float* __restrict__ scores, const float* __restrict__ deltas,
    const float* __restrict__ anchors, const float* __restrict__ im_info,
    float* __restrict__ out, float* __restrict__ boxesb, float* __restrict__ ssb)
{
    const int b = blockIdx.x, tid = threadIdx.x;
    const float* s = scores + (size_t)b * NSC;
    float best = -INFINITY;
    int bidx = 0;
    for (int i = tid; i < NSC; i += 256) {
        float v = s[i];
        if (v > best) { best = v; bidx = i; }   // keeps first occurrence per thread
    }
    __shared__ float sv[256];
    __shared__ int   si[256];
    sv[tid] = best; si[tid] = bidx;
    __syncthreads();
    for (int stp = 128; stp > 0; stp >>= 1) {
        if (tid < stp) {
            float ov = sv[tid + stp]; int oi = si[tid + stp];
            if (ov > sv[tid] || (ov == sv[tid] && oi < si[tid])) { sv[tid] = ov; si[tid] = oi; }
        }
        __syncthreads();
    }
    if (tid == 0) {
        float ss = sv[0];
        int id = si[0];
        int kprime = id >> 2, aprime = id & 3;       // reference's (buggy) reinterpretation
        int hp = kprime / 38, wp = kprime - hp * 38;
        float im = im_info[0];
        float gx = (float)wp * 16.0f, gy = (float)hp * 16.0f;
#pragma unroll
        for (int j = 0; j < 4; ++j) {
            float shift = ((j & 1) == 0) ? gx : gy;
            float prop = anchors[aprime * 4 + j] + shift;
            float dlt = deltas[((size_t)b * 16 + (aprime * 4 + j)) * HW2 + kprime];
            float bx = (prop + dlt) * im;
            out[b * 9 + j]     = truncf(bx / im);
            out[b * 9 + 4 + j] = bx;
            boxesb[b * 4 + j]  = bx;
        }
        out[b * 9 + 8] = ss;
        ssb[b] = ss;
    }
}

// ---------------- proposal loss (nv = 1) ----------------
__global__ void loss_kernel(const int* __restrict__ central_pos,
                            const float* __restrict__ gt,
                            const float* __restrict__ boxesb,
                            const float* __restrict__ ssb,
                            float* __restrict__ out)
{
    if (threadIdx.x != 0 || blockIdx.x != 0) return;
    int idx = central_pos[0];                 // FRAMES_PER_VIDEO*0 + central_pos
    bool valid = idx < NFRAMES;
    int idxc = min(max(idx, 0), NFRAMES - 1);
    float vb0 = boxesb[idxc * 4 + 0], vb1 = boxesb[idxc * 4 + 1];
    float vb2 = boxesb[idxc * 4 + 2], vb3 = boxesb[idxc * 4 + 3];
    float vs = ssb[idxc];
    float g0 = gt[0], g1 = gt[1], g2 = gt[2], g3 = gt[3];
    float xi1 = fmaxf(g0, vb0), yi1 = fmaxf(g1, vb1);
    float xi2 = fmaxf(g2, vb2), yi2 = fmaxf(g3, vb3);   // reference uses maximum here too
    float inter = (xi2 - xi1) * (yi2 - yi1);
    float a1 = (g2 - g0) * (g3 - g1);
    float a2 = (vb2 - vb0) * (vb3 - vb1);
    float iou = inter / (a1 + a2 - inter);
    float lv = (iou > 0.7f) ? -logf(vs + 1e-5f) : -logf(1.0f - vs + 1e-5f);
    out[NFRAMES * 9] = valid ? lv : 0.0f;
}

// ---------------- host launcher ----------------
extern "C" void kernel_launch(void* const* d_in, const int* in_sizes, int n_in,
                              void* d_out, int out_size, void* d_ws, size_t ws_size,
                              hipStream_t stream) {
    const float* base_feat   = (const float*)d_in[0];
    const int*   central_pos = (const int*)d_in[1];
    const float* im_info     = (const float*)d_in[2];
    const float* gt_boxes    = (const float*)d_in[3];
    const float* W1 = (const float*)d_in[4];
    const float* b1 = (const float*)d_in[5];
    const float* Wc = (const float*)d_in[6];
    const float* bc = (const float*)d_in[7];
    const float* Wb = (const float*)d_in[8];
    const float* bb = (const float*)d_in[9];
    const float* anchors = (const float*)d_in[10];
    float* out = (float*)d_out;

    float* ws     = (float*)d_ws;
    float* xbuf   = ws;                                      // CHUNK*128*1524
    float* scores = xbuf + (size_t)CHUNK * COUT1 * PSTR;     // 300*5776
    float* deltas = scores + (size_t)NFRAMES * NSC;          // 300*16*1444
    float* w1r    = deltas + (size_t)NFRAMES * 16 * HW2;     // 131072
    float* wl     = w1r + 131072;                            // 12288
    float* boxesb = wl + 12288;                              // 1200
    float* ssb    = boxesb + NFRAMES * 4;                    // 300

    repack_w1<<<512, 256, 0, stream>>>(W1, w1r);
    repack_wl<<<48, 256, 0, stream>>>(Wc, Wb, wl);

    for (int c = 0; c < NCHUNKS; ++c) {
        int f0 = c * CHUNK;
        conv1_kernel<<<dim3(12, 1, CHUNK), 256, 0, stream>>>(base_feat, w1r, b1, xbuf, f0);
        stage2_kernel<<<dim3(19, CHUNK), 256, 0, stream>>>(xbuf, wl, bc, bb, scores, deltas, f0);
    }
    argmax_kernel<<<NFRAMES, 256, 0, stream>>>(scores, deltas, anchors, im_info, out, boxesb, ssb);
    loss_kernel<<<1, 64, 0, stream>>>(central_pos, gt_boxes, boxesb, ssb, out);
}

// Round 2
// 2805.531 us; speedup vs baseline: 1.3624x; 1.3624x over previous
//
#include <hip/hip_runtime.h>
#include <math.h>

#define CIN 256
#define HIN 38
#define WIN 38
#define NFRAMES 300
#define COUT1 128
#define P1 1521      // 39*39
#define PSTR 1524    // padded spatial stride
#define HW2 1444     // 38*38
#define NSC 5776     // 4*38*38
#define CHUNK 75
#define NCHUNKS 4
#define W1F_LO 131072   // offset (in halves) of lo-part in W1f

typedef _Float16 half8 __attribute__((ext_vector_type(8)));
typedef float    f32x4 __attribute__((ext_vector_type(4)));

// ---------------- weight repack: fragment-major packed hi/lo f16 ----------------
// W1f layout: [slice 0..32)[mt 0..8)[lane 0..64)[j 0..8)  (hi at 0, lo at +131072)
// k = slice*32 + (lane>>4)*8 + j ; co = mt*16 + (lane&15) ; ci = k>>2 ; kid = k&3
// weights scaled by 64 so the lo term stays fp16-normal.
__global__ void repack_w1f(const float* __restrict__ W1, _Float16* __restrict__ W1f) {
    int e = blockIdx.x * 256 + threadIdx.x;          // < 131072
    int j  = e & 7;
    int ln = (e >> 3) & 63;
    int mt = (e >> 9) & 7;
    int s  = e >> 12;
    int k  = s * 32 + (ln >> 4) * 8 + j;
    int co = mt * 16 + (ln & 15);
    int kid = k & 3, ci = k >> 2;
    float v = W1[((co * 256) + ci) * 4 + kid] * 64.0f;
    _Float16 h = (_Float16)v;
    W1f[e]          = h;
    W1f[e + W1F_LO] = (_Float16)(v - (float)h);
}

// Wl[((ci4*4+kid)*24 + ch)*4 + j], ci = ci4*4+j ; ch<8 -> Wc, else Wb
__global__ void repack_wl(const float* __restrict__ Wc, const float* __restrict__ Wb,
                          float* __restrict__ Wl) {
    int e = blockIdx.x * 256 + threadIdx.x;          // < 12288
    int j = e & 3;
    int r = e >> 2;
    int ch = r % 24;
    int q  = r / 24;
    int kid = q & 3, ci4 = q >> 2;
    int ci = ci4 * 4 + j;
    float v = (ch < 8) ? Wc[(ch * 128 + ci) * 4 + kid]
                       : Wb[((ch - 8) * 128 + ci) * 4 + kid];
    Wl[e] = v;
}

// ---------------- conv1 via split-fp16 MFMA ----------------
// per-frame GEMM C[128 co][1521 px], K=1024 (k = ci*4+kid).
// block: 128 co x 128 px, 4 waves, wave = 8 mt x 2 nt tiles of 16x16x32 MFMA.
// split: v = hi + lo (fp16); C = Ah*Bh + Al*Bh + Ah*Bl (lo*lo dropped, ~2^-22).
// A (weights) read fragment-major straight from L2; B staged in LDS per BK=32 slice.
__global__ __launch_bounds__(256) void conv1_mfma(
    const float* __restrict__ bf, const _Float16* __restrict__ W1f,
    const float* __restrict__ b1, float* __restrict__ xout, int frame0)
{
    __shared__ __align__(16) _Float16 Bs_hi[4096];   // [nt][lane][j]
    __shared__ __align__(16) _Float16 Bs_lo[4096];

    const int tid  = threadIdx.x;
    const int wave = tid >> 6, ln = tid & 63;
    const int nt0  = wave * 2;
    const int fz = blockIdx.z;
    const int b  = frame0 + fz;
    const int p0 = blockIdx.x * 128;
    const float* bfb = bf + (size_t)b * (CIN * HIN * WIN);

    // per-thread staging precompute: 2 slots (tid, tid+256)
    int  kofs[2][4];
    bool kok[2][4];
    int  sbase[2], saddr[2];
#pragma unroll
    for (int r = 0; r < 2; ++r) {
        int slot = tid + r * 256;
        int ln_s = slot & 63, nt = slot >> 6;
        int n = (nt << 4) | (ln_s & 15);
        int quad = ln_s >> 4;
        int p = p0 + n;
        bool pok = p < P1;
        int pp = pok ? p : 0;
        int h = pp / 39, w = pp - h * 39;
#pragma unroll
        for (int kid = 0; kid < 4; ++kid) {
            int hh = h + (kid >> 1) - 1;
            int ww = w + (kid & 1) - 1;
            kok[r][kid]  = pok && ((unsigned)hh < 38u) && ((unsigned)ww < 38u);
            kofs[r][kid] = hh * 38 + ww;
        }
        sbase[r] = quad * 2 * 1444;     // ci offset within slice
        saddr[r] = slot * 8;            // LDS half index (16B/slot)
    }

    f32x4 acc[8][2];
#pragma unroll
    for (int mt = 0; mt < 8; ++mt) {
        acc[mt][0] = (f32x4)0.0f;
        acc[mt][1] = (f32x4)0.0f;
    }

    for (int s = 0; s < 32; ++s) {
        // ---- stage B slice: k = s*32 + quad*8 + j ; ci = k>>2 ; kid = j&3 ----
        const float* bsrc = bfb + (size_t)s * 8 * 1444;   // (k0>>2)*1444
#pragma unroll
        for (int r = 0; r < 2; ++r) {
            const float* sp = bsrc + sbase[r];
            half8 hv, lv;
#pragma unroll
            for (int j = 0; j < 8; ++j) {
                int kid = j & 3;
                float v = kok[r][kid] ? sp[(j >> 2) * 1444 + kofs[r][kid]] : 0.0f;
                v *= 32.0f;                                 // keep lo fp16-normal
                _Float16 hh = (_Float16)v;
                hv[j] = hh;
                lv[j] = (_Float16)(v - (float)hh);
            }
            *(half8*)&Bs_hi[saddr[r]] = hv;
            *(half8*)&Bs_lo[saddr[r]] = lv;
        }
        __syncthreads();

        // ---- compute: 48 MFMAs / wave ----
        half8 bh0 = *(half8*)&Bs_hi[(nt0 * 64 + ln) * 8];
        half8 bl0 = *(half8*)&Bs_lo[(nt0 * 64 + ln) * 8];
        half8 bh1 = *(half8*)&Bs_hi[((nt0 + 1) * 64 + ln) * 8];
        half8 bl1 = *(half8*)&Bs_lo[((nt0 + 1) * 64 + ln) * 8];
        const _Float16* wp = W1f + (size_t)s * 4096 + ln * 8;
#pragma unroll
        for (int mt = 0; mt < 8; ++mt) {
            half8 ah = *(const half8*)(wp + mt * 512);
            half8 al = *(const half8*)(wp + W1F_LO + mt * 512);
            acc[mt][0] = __builtin_amdgcn_mfma_f32_16x16x32_f16(ah, bh0, acc[mt][0], 0, 0, 0);
            acc[mt][1] = __builtin_amdgcn_mfma_f32_16x16x32_f16(ah, bh1, acc[mt][1], 0, 0, 0);
            acc[mt][0] = __builtin_amdgcn_mfma_f32_16x16x32_f16(al, bh0, acc[mt][0], 0, 0, 0);
            acc[mt][1] = __builtin_amdgcn_mfma_f32_16x16x32_f16(al, bh1, acc[mt][1], 0, 0, 0);
            acc[mt][0] = __builtin_amdgcn_mfma_f32_16x16x32_f16(ah, bl0, acc[mt][0], 0, 0, 0);
            acc[mt][1] = __builtin_amdgcn_mfma_f32_16x16x32_f16(ah, bl1, acc[mt][1], 0, 0, 0);
        }
        __syncthreads();
    }

    // ---- epilogue: scale back (inputs x32 * weights x64), bias + relu ----
    const float sc = 1.0f / 2048.0f;
    const int colp = ln & 15, rq = ln >> 4;
#pragma unroll
    for (int mt = 0; mt < 8; ++mt)
#pragma unroll
        for (int i = 0; i < 2; ++i) {
            int p = p0 + (nt0 + i) * 16 + colp;
            if (p < P1) {
#pragma unroll
                for (int r = 0; r < 4; ++r) {
                    int co = mt * 16 + rq * 4 + r;
                    xout[((size_t)fz * COUT1 + co) * PSTR + p] =
                        fmaxf(fmaf(acc[mt][i][r], sc, b1[co]), 0.0f);
                }
            }
        }
}

// ---------------- stage2: cls + deltas + scores (unchanged) ----------------
__global__ __launch_bounds__(256) void stage2_kernel(
    const float* __restrict__ x, const float* __restrict__ Wl,
    const float* __restrict__ bcv, const float* __restrict__ bbv,
    float* __restrict__ scores, float* __restrict__ deltas, int frame0)
{
    __shared__ __align__(16) float xs[3][39][132];
    __shared__ float clsrow[2][8][38];
    const int tid = threadIdx.x;
    const int h0 = blockIdx.x * 2;
    const int fz = blockIdx.y;
    const int b  = frame0 + fz;
    const float* xb = x + (size_t)fz * COUT1 * PSTR;

    for (int e = tid; e < 128 * 117; e += 256) {
        int ci = e / 117, off = e - ci * 117;
        ((float*)xs)[off * 132 + ci] = xb[ci * PSTR + h0 * 39 + off];
    }
    __syncthreads();

    int w = 0, chg = 0;
    const bool active = tid < 228;
    if (active) { w = tid / 6; chg = tid - w * 6; }

    float acc[2][4];
#pragma unroll
    for (int r = 0; r < 2; ++r)
#pragma unroll
        for (int cc = 0; cc < 4; ++cc) {
            int ch = chg * 4 + cc;
            acc[r][cc] = (ch < 8) ? bcv[ch] : bbv[ch - 8];
        }

    for (int ci4 = 0; ci4 < 32; ++ci4) {
#pragma unroll
        for (int kid = 0; kid < 4; ++kid) {
            int kh = kid >> 1, kw = kid & 1;
            float4 x0 = *(const float4*)&xs[kh][w + kw][ci4 * 4];
            float4 x1 = *(const float4*)&xs[kh + 1][w + kw][ci4 * 4];
#pragma unroll
            for (int cc = 0; cc < 4; ++cc) {
                float4 wv = *(const float4*)&Wl[(((ci4 * 4 + kid) * 24) + chg * 4 + cc) * 4];
                acc[0][cc] += x0.x * wv.x + x0.y * wv.y + x0.z * wv.z + x0.w * wv.w;
                acc[1][cc] += x1.x * wv.x + x1.y * wv.y + x1.z * wv.z + x1.w * wv.w;
            }
        }
    }

    if (active) {
#pragma unroll
        for (int r = 0; r < 2; ++r) {
            int h = h0 + r;
#pragma unroll
            for (int cc = 0; cc < 4; ++cc) {
                int ch = chg * 4 + cc;
                if (ch < 8) clsrow[r][ch][w] = acc[r][cc];
                else deltas[((size_t)b * 16 + (ch - 8)) * HW2 + h * 38 + w] = acc[r][cc];
            }
        }
    }
    __syncthreads();

    for (int e = tid; e < 304; e += 256) {
        int r = e / 152, t2 = e - r * 152;
        int a = t2 & 3, w2 = t2 >> 2;
        float z1 = clsrow[r][a][w2];
        float z2 = clsrow[r][a + 4][w2];
        float mx = fmaxf(z1, z2);
        float e1 = expf(z1 - mx), e2 = expf(z2 - mx);
        scores[(size_t)b * NSC + a * HW2 + (h0 + r) * 38 + w2] = e2 / (e1 + e2);
    }
}

// ---------------- per-frame argmax + box decode (unchanged) ----------------
__global__ __launch_bounds__(256) void argmax_kernel(
    const float* __restrict__ scores, const float* __restrict__ deltas,
    const float* __restrict__ anchors, const float* __restrict__ im_info,
    float* __restrict__ out, float* __restrict__ boxesb, float* __restrict__ ssb)
{
    const int b = blockIdx.x, tid = threadIdx.x;
    const float* s = scores + (size_t)b * NSC;
    float best = -INFINITY;
    int bidx = 0;
    for (int i = tid; i < NSC; i += 256) {
        float v = s[i];
        if (v > best) { best = v; bidx = i; }
    }
    __shared__ float sv[256];
    __shared__ int   si[256];
    sv[tid] = best; si[tid] = bidx;
    __syncthreads();
    for (int stp = 128; stp > 0; stp >>= 1) {
        if (tid < stp) {
            float ov = sv[tid + stp]; int oi = si[tid + stp];
            if (ov > sv[tid] || (ov == sv[tid] && oi < si[tid])) { sv[tid] = ov; si[tid] = oi; }
        }
        __syncthreads();
    }
    if (tid == 0) {
        float ss = sv[0];
        int id = si[0];
        int kprime = id >> 2, aprime = id & 3;
        int hp = kprime / 38, wp = kprime - hp * 38;
        float im = im_info[0];
        float gx = (float)wp * 16.0f, gy = (float)hp * 16.0f;
#pragma unroll
        for (int j = 0; j < 4; ++j) {
            float shift = ((j & 1) == 0) ? gx : gy;
            float prop = anchors[aprime * 4 + j] + shift;
            float dlt = deltas[((size_t)b * 16 + (aprime * 4 + j)) * HW2 + kprime];
            float bx = (prop + dlt) * im;
            out[b * 9 + j]     = truncf(bx / im);
            out[b * 9 + 4 + j] = bx;
            boxesb[b * 4 + j]  = bx;
        }
        out[b * 9 + 8] = ss;
        ssb[b] = ss;
    }
}

// ---------------- proposal loss (unchanged) ----------------
__global__ void loss_kernel(const int* __restrict__ central_pos,
                            const float* __restrict__ gt,
                            const float* __restrict__ boxesb,
                            const float* __restrict__ ssb,
                            float* __restrict__ out)
{
    if (threadIdx.x != 0 || blockIdx.x != 0) return;
    int idx = central_pos[0];
    bool valid = idx < NFRAMES;
    int idxc = min(max(idx, 0), NFRAMES - 1);
    float vb0 = boxesb[idxc * 4 + 0], vb1 = boxesb[idxc * 4 + 1];
    float vb2 = boxesb[idxc * 4 + 2], vb3 = boxesb[idxc * 4 + 3];
    float vs = ssb[idxc];
    float g0 = gt[0], g1 = gt[1], g2 = gt[2], g3 = gt[3];
    float xi1 = fmaxf(g0, vb0), yi1 = fmaxf(g1, vb1);
    float xi2 = fmaxf(g2, vb2), yi2 = fmaxf(g3, vb3);
    float inter = (xi2 - xi1) * (yi2 - yi1);
    float a1 = (g2 - g0) * (g3 - g1);
    float a2 = (vb2 - vb0) * (vb3 - vb1);
    float iou = inter / (a1 + a2 - inter);
    float lv = (iou > 0.7f) ? -logf(vs + 1e-5f) : -logf(1.0f - vs + 1e-5f);
    out[NFRAMES * 9] = valid ? lv : 0.0f;
}

// ---------------- host launcher ----------------
extern "C" void kernel_launch(void* const* d_in, const int* in_sizes, int n_in,
                              void* d_out, int out_size, void* d_ws, size_t ws_size,
                              hipStream_t stream) {
    const float* base_feat   = (const float*)d_in[0];
    const int*   central_pos = (const int*)d_in[1];
    const float* im_info     = (const float*)d_in[2];
    const float* gt_boxes    = (const float*)d_in[3];
    const float* W1 = (const float*)d_in[4];
    const float* b1 = (const float*)d_in[5];
    const float* Wc = (const float*)d_in[6];
    const float* bc = (const float*)d_in[7];
    const float* Wb = (const float*)d_in[8];
    const float* bb = (const float*)d_in[9];
    const float* anchors = (const float*)d_in[10];
    float* out = (float*)d_out;

    float* ws     = (float*)d_ws;
    float* xbuf   = ws;                                      // CHUNK*128*1524
    float* scores = xbuf + (size_t)CHUNK * COUT1 * PSTR;     // 300*5776
    float* deltas = scores + (size_t)NFRAMES * NSC;          // 300*16*1444
    float* w1r    = deltas + (size_t)NFRAMES * 16 * HW2;     // 131072 floats = 262144 halves
    float* wl     = w1r + 131072;                            // 12288
    float* boxesb = wl + 12288;                              // 1200
    float* ssb    = boxesb + NFRAMES * 4;                    // 300
    _Float16* w1f = (_Float16*)w1r;

    repack_w1f<<<512, 256, 0, stream>>>(W1, w1f);
    repack_wl<<<48, 256, 0, stream>>>(Wc, Wb, wl);

    for (int c = 0; c < NCHUNKS; ++c) {
        int f0 = c * CHUNK;
        conv1_mfma<<<dim3(12, 1, CHUNK), 256, 0, stream>>>(base_feat, w1f, b1, xbuf, f0);
        stage2_kernel<<<dim3(19, CHUNK), 256, 0, stream>>>(xbuf, wl, bc, bb, scores, deltas, f0);
    }
    argmax_kernel<<<NFRAMES, 256, 0, stream>>>(scores, deltas, anchors, im_info, out, boxesb, ssb);
    loss_kernel<<<1, 64, 0, stream>>>(central_pos, gt_boxes, boxesb, ssb, out);
}

// Round 3
// 1967.500 us; speedup vs baseline: 1.9427x; 1.4259x over previous
//
#include <hip/hip_runtime.h>
#include <math.h>

#define CIN 256
#define HIN 38
#define WIN 38
#define NFRAMES 300
#define COUT1 128
#define P1 1521      // 39*39
#define PSTR 1524    // padded spatial stride
#define HW2 1444     // 38*38
#define NSC 5776     // 4*38*38
#define CHUNK 75
#define NCHUNKS 4
#define W1F_LO 131072   // offset (in halves) of lo-part in W1f
#define W2F_LO 16384    // offset (in halves) of lo-part in W2f

typedef _Float16 half8 __attribute__((ext_vector_type(8)));
typedef _Float16 half2v __attribute__((ext_vector_type(2)));
typedef float    f32x4 __attribute__((ext_vector_type(4)));

union H2U { unsigned int u; half2v h; };

// ---------------- weight repack: fragment-major packed hi/lo f16 ----------------
// W1f: [slice 0..32)[mt 0..8)[lane 0..64)[j 0..8), hi at 0, lo at +W1F_LO.
// k = slice*32 + (lane>>4)*8 + j ; co = mt*16 + (lane&15) ; ci = k>>2 ; kid = k&3
__global__ void repack_w1f(const float* __restrict__ W1, _Float16* __restrict__ W1f) {
    int e = blockIdx.x * 256 + threadIdx.x;          // < 131072
    int j  = e & 7;
    int ln = (e >> 3) & 63;
    int mt = (e >> 9) & 7;
    int s  = e >> 12;
    int k  = s * 32 + (ln >> 4) * 8 + j;
    int co = mt * 16 + (ln & 15);
    int kid = k & 3, ci = k >> 2;
    float v = W1[((co * 256) + ci) * 4 + kid] * 64.0f;
    _Float16 h = (_Float16)v;
    W1f[e]          = h;
    W1f[e + W1F_LO] = (_Float16)(v - (float)h);
}

// W2f: [slice 0..16)[mt 0..2)[lane][j]; ch = mt*16+(lane&15): 0..7 cls, 8..23 delta, >=24 zero
__global__ void repack_w2f(const float* __restrict__ Wc, const float* __restrict__ Wb,
                           _Float16* __restrict__ W2f) {
    int e = blockIdx.x * 256 + threadIdx.x;          // < 16384
    int j  = e & 7;
    int ln = (e >> 3) & 63;
    int mt = (e >> 9) & 1;
    int s  = e >> 10;
    int k  = s * 32 + (ln >> 4) * 8 + j;
    int ch = mt * 16 + (ln & 15);
    int ci = k >> 2, kid = k & 3;
    float v = 0.0f;
    if (ch < 8)       v = Wc[(ch * 128 + ci) * 4 + kid];
    else if (ch < 24) v = Wb[((ch - 8) * 128 + ci) * 4 + kid];
    v *= 64.0f;
    _Float16 h = (_Float16)v;
    W2f[e]          = h;
    W2f[e + W2F_LO] = (_Float16)(v - (float)h);
}

// ---------------- conv1: split-f16 MFMA, m97-style LDS double-stage ----------------
// per-frame GEMM C[128co][1521px], K=1024 (k = ci*4+kid), 32 slices of BK=32.
// block 256 = 4 waves in 2x2 arrangement; wave tile 64co x 64px (4mt x 4nt of 16x16x32).
// x written as packed {hi,lo} f16 of (relu(y)*32) for stage2 consumption.
__global__ __launch_bounds__(256) void conv1_mfma(
    const float* __restrict__ bf, const _Float16* __restrict__ W1f,
    const float* __restrict__ b1, unsigned int* __restrict__ xout, int frame0)
{
    __shared__ __align__(16) _Float16 As[8192];   // hi [0,4096): mt*512+ln*8 ; lo +4096
    __shared__ __align__(16) _Float16 Bs[8192];   // hi: slot*8, slot=nt*64+ln ; lo +4096

    const int tid  = threadIdx.x;
    const int wave = tid >> 6, ln = tid & 63;
    const int wrow = wave >> 1, wcol = wave & 1;
    const int fz = blockIdx.y;
    const int b  = frame0 + fz;
    const int p0 = blockIdx.x * 128;
    const float* bfb = bf + (size_t)b * (CIN * HIN * WIN);

    // B staging geometry: 2 slots/thread; slot = tid + 256r
    int  addr1[2][8];
    bool kok[2][4];
    int  saddr[2];
#pragma unroll
    for (int r = 0; r < 2; ++r) {
        int slot = tid + r * 256;
        int ln_s = slot & 63, nt = slot >> 6;
        int p = p0 + nt * 16 + (ln_s & 15);
        int quad = ln_s >> 4;
        bool pok = p < P1;
        int pp = pok ? p : 0;
        int h = pp / 39, w = pp - h * 39;
#pragma unroll
        for (int kid = 0; kid < 4; ++kid) {
            int hh = h + (kid >> 1) - 1;
            int ww = w + (kid & 1) - 1;
            kok[r][kid] = pok && ((unsigned)hh < 38u) && ((unsigned)ww < 38u);
            int ko = hh * 38 + ww;
#pragma unroll
            for (int t = 0; t < 2; ++t)
                addr1[r][t * 4 + kid] = quad * 2 * 1444 + t * 1444 + ko;
        }
        saddr[r] = slot * 8;
    }

    f32x4 acc[4][4];
#pragma unroll
    for (int i = 0; i < 4; ++i)
#pragma unroll
        for (int j = 0; j < 4; ++j) acc[i][j] = (f32x4)0.0f;

    float bn[2][8];
    half8 an[4];

    // ---- prologue: load + stage slice 0 ----
    {
        const float* bsrc = bfb;
#pragma unroll
        for (int r = 0; r < 2; ++r)
#pragma unroll
            for (int j = 0; j < 8; ++j)
                bn[r][j] = kok[r][j & 3] ? bsrc[addr1[r][j]] : 0.0f;
#pragma unroll
        for (int f = 0; f < 4; ++f) {
            int o = (tid + f * 256) * 8;
            const _Float16* g = (f < 2) ? (W1f + o) : (W1f + W1F_LO + (o - 4096));
            an[f] = *(const half8*)g;
        }
#pragma unroll
        for (int r = 0; r < 2; ++r) {
            half8 hv, lv;
#pragma unroll
            for (int j = 0; j < 8; ++j) {
                float v = bn[r][j] * 32.0f;
                _Float16 h = (_Float16)v;
                hv[j] = h; lv[j] = (_Float16)(v - (float)h);
            }
            *(half8*)&Bs[saddr[r]] = hv;
            *(half8*)&Bs[4096 + saddr[r]] = lv;
        }
#pragma unroll
        for (int f = 0; f < 4; ++f)
            *(half8*)&As[(tid + f * 256) * 8] = an[f];
    }
    __syncthreads();

    for (int s = 0; s < 32; ++s) {
        // ---- prefetch slice s+1 into registers (latency hidden by compute) ----
        if (s < 31) {
            const float* bsrc = bfb + (size_t)(s + 1) * 8 * 1444;
#pragma unroll
            for (int r = 0; r < 2; ++r)
#pragma unroll
                for (int j = 0; j < 8; ++j)
                    bn[r][j] = kok[r][j & 3] ? bsrc[addr1[r][j]] : 0.0f;
            const _Float16* wsl = W1f + (size_t)(s + 1) * 4096;
#pragma unroll
            for (int f = 0; f < 4; ++f) {
                int o = (tid + f * 256) * 8;
                const _Float16* g = (f < 2) ? (wsl + o) : (wsl + W1F_LO + (o - 4096));
                an[f] = *(const half8*)g;
            }
        }
        // ---- compute slice s ----
        half8 af_h[4], af_l[4], bf_h[4], bf_l[4];
#pragma unroll
        for (int t = 0; t < 4; ++t) {
            int mtile = wrow * 4 + t;
            af_h[t] = *(const half8*)&As[mtile * 512 + ln * 8];
            af_l[t] = *(const half8*)&As[4096 + mtile * 512 + ln * 8];
            int ntile = wcol * 4 + t;
            bf_h[t] = *(const half8*)&Bs[(ntile * 64 + ln) * 8];
            bf_l[t] = *(const half8*)&Bs[4096 + (ntile * 64 + ln) * 8];
        }
#pragma unroll
        for (int i = 0; i < 4; ++i)
#pragma unroll
            for (int j = 0; j < 4; ++j)
                acc[i][j] = __builtin_amdgcn_mfma_f32_16x16x32_f16(af_h[i], bf_h[j], acc[i][j], 0, 0, 0);
#pragma unroll
        for (int i = 0; i < 4; ++i)
#pragma unroll
            for (int j = 0; j < 4; ++j)
                acc[i][j] = __builtin_amdgcn_mfma_f32_16x16x32_f16(af_l[i], bf_h[j], acc[i][j], 0, 0, 0);
#pragma unroll
        for (int i = 0; i < 4; ++i)
#pragma unroll
            for (int j = 0; j < 4; ++j)
                acc[i][j] = __builtin_amdgcn_mfma_f32_16x16x32_f16(af_h[i], bf_l[j], acc[i][j], 0, 0, 0);

        // ---- stage s+1 into LDS ----
        if (s < 31) {
            __syncthreads();
#pragma unroll
            for (int r = 0; r < 2; ++r) {
                half8 hv, lv;
#pragma unroll
                for (int j = 0; j < 8; ++j) {
                    float v = bn[r][j] * 32.0f;
                    _Float16 h = (_Float16)v;
                    hv[j] = h; lv[j] = (_Float16)(v - (float)h);
                }
                *(half8*)&Bs[saddr[r]] = hv;
                *(half8*)&Bs[4096 + saddr[r]] = lv;
            }
#pragma unroll
            for (int f = 0; f < 4; ++f)
                *(half8*)&As[(tid + f * 256) * 8] = an[f];
            __syncthreads();
        }
    }

    // ---- epilogue: descale, bias, relu, pack {hi,lo} of (x*32) ----
    const float sc = 1.0f / 2048.0f;
    const int rq = ln >> 4, cl = ln & 15;
#pragma unroll
    for (int i = 0; i < 4; ++i) {
#pragma unroll
        for (int j = 0; j < 4; ++j) {
            int p = p0 + (wcol * 4 + j) * 16 + cl;
            if (p < P1) {
#pragma unroll
                for (int rr = 0; rr < 4; ++rr) {
                    int co = (wrow * 4 + i) * 16 + rq * 4 + rr;
                    float t = fmaxf(fmaf(acc[i][j][rr], sc, b1[co]), 0.0f) * 32.0f;
                    H2U u;
                    u.h[0] = (_Float16)t;
                    u.h[1] = (_Float16)(t - (float)u.h[0]);
                    xout[((size_t)fz * COUT1 + co) * PSTR + p] = u.u;
                }
            }
        }
    }
}

// ---------------- stage2: cls+deltas+scores via split-f16 MFMA ----------------
// per-frame GEMM C[32ch(24 used)][1444px], K=512 (k=ci*4+kid), 16 slices of 32.
// block 256 = 4 waves; wave covers 32px (nt = wave*2 + {0,1}), both mt tiles.
__global__ __launch_bounds__(256) void stage2_mfma(
    const unsigned int* __restrict__ xq, const _Float16* __restrict__ W2f,
    const float* __restrict__ bcv, const float* __restrict__ bbv,
    float* __restrict__ scores, float* __restrict__ deltas, int frame0)
{
    __shared__ __align__(16) _Float16 Bs[8192];
    __shared__ float clsb[8][128];

    const int tid  = threadIdx.x;
    const int wave = tid >> 6, ln = tid & 63;
    const int fz = blockIdx.y;
    const int b  = frame0 + fz;
    const int p0 = blockIdx.x * 128;
    const unsigned int* xb = xq + (size_t)fz * COUT1 * PSTR;

    // staging geometry
    int  addr2[2][8];
    bool sok[2];
    int  saddr[2];
#pragma unroll
    for (int r = 0; r < 2; ++r) {
        int slot = tid + r * 256;
        int ln_s = slot & 63, nt = slot >> 6;
        int p = p0 + nt * 16 + (ln_s & 15);
        int quad = ln_s >> 4;
        sok[r] = p < HW2;
        int pp = sok[r] ? p : 0;
        int h = pp / 38, w = pp - h * 38;
#pragma unroll
        for (int kid = 0; kid < 4; ++kid) {
            int ko = (h + (kid >> 1)) * 39 + (w + (kid & 1));
#pragma unroll
            for (int t = 0; t < 2; ++t)
                addr2[r][t * 4 + kid] = (quad * 2 + t) * PSTR + ko;
        }
        saddr[r] = slot * 8;
    }

    f32x4 acc[2][2];
    acc[0][0] = (f32x4)0.0f; acc[0][1] = (f32x4)0.0f;
    acc[1][0] = (f32x4)0.0f; acc[1][1] = (f32x4)0.0f;

    unsigned int bu[2][8];
    // prologue: slice 0
    {
        const unsigned int* row = xb;
#pragma unroll
        for (int r = 0; r < 2; ++r)
#pragma unroll
            for (int j = 0; j < 8; ++j)
                bu[r][j] = sok[r] ? row[addr2[r][j]] : 0u;
#pragma unroll
        for (int r = 0; r < 2; ++r) {
            half8 hv, lv;
#pragma unroll
            for (int j = 0; j < 8; ++j) {
                H2U t; t.u = bu[r][j];
                hv[j] = t.h[0]; lv[j] = t.h[1];
            }
            *(half8*)&Bs[saddr[r]] = hv;
            *(half8*)&Bs[4096 + saddr[r]] = lv;
        }
    }
    __syncthreads();

    for (int s = 0; s < 16; ++s) {
        if (s < 15) {
            const unsigned int* row = xb + (size_t)(s + 1) * 8 * PSTR;
#pragma unroll
            for (int r = 0; r < 2; ++r)
#pragma unroll
                for (int j = 0; j < 8; ++j)
                    bu[r][j] = sok[r] ? row[addr2[r][j]] : 0u;
        }
        // A fragments straight from global (64 KB total, L1/L2-hot)
        half8 a_h[2], a_l[2], b_h[2], b_l[2];
#pragma unroll
        for (int mt = 0; mt < 2; ++mt) {
            const _Float16* wp = W2f + ((size_t)(s * 2 + mt) * 64 + ln) * 8;
            a_h[mt] = *(const half8*)wp;
            a_l[mt] = *(const half8*)(wp + W2F_LO);
        }
#pragma unroll
        for (int t = 0; t < 2; ++t) {
            int ntile = wave * 2 + t;
            b_h[t] = *(const half8*)&Bs[(ntile * 64 + ln) * 8];
            b_l[t] = *(const half8*)&Bs[4096 + (ntile * 64 + ln) * 8];
        }
#pragma unroll
        for (int i = 0; i < 2; ++i)
#pragma unroll
            for (int j = 0; j < 2; ++j)
                acc[i][j] = __builtin_amdgcn_mfma_f32_16x16x32_f16(a_h[i], b_h[j], acc[i][j], 0, 0, 0);
#pragma unroll
        for (int i = 0; i < 2; ++i)
#pragma unroll
            for (int j = 0; j < 2; ++j)
                acc[i][j] = __builtin_amdgcn_mfma_f32_16x16x32_f16(a_l[i], b_h[j], acc[i][j], 0, 0, 0);
#pragma unroll
        for (int i = 0; i < 2; ++i)
#pragma unroll
            for (int j = 0; j < 2; ++j)
                acc[i][j] = __builtin_amdgcn_mfma_f32_16x16x32_f16(a_h[i], b_l[j], acc[i][j], 0, 0, 0);

        if (s < 15) {
            __syncthreads();
#pragma unroll
            for (int r = 0; r < 2; ++r) {
                half8 hv, lv;
#pragma unroll
                for (int j = 0; j < 8; ++j) {
                    H2U t; t.u = bu[r][j];
                    hv[j] = t.h[0]; lv[j] = t.h[1];
                }
                *(half8*)&Bs[saddr[r]] = hv;
                *(half8*)&Bs[4096 + saddr[r]] = lv;
            }
            __syncthreads();
        }
    }

    // ---- epilogue ----
    const float sc = 1.0f / 2048.0f;
    const int rq = ln >> 4, cl = ln & 15;
#pragma unroll
    for (int mt = 0; mt < 2; ++mt) {
#pragma unroll
        for (int t = 0; t < 2; ++t) {
            int lpx = (wave * 2 + t) * 16 + cl;
            int p = p0 + lpx;
#pragma unroll
            for (int rr = 0; rr < 4; ++rr) {
                int ch = mt * 16 + rq * 4 + rr;
                float v = acc[mt][t][rr] * sc;
                if (ch < 8) {
                    clsb[ch][lpx] = v + bcv[ch];
                } else if (ch < 24 && p < HW2) {
                    deltas[((size_t)b * 16 + (ch - 8)) * HW2 + p] = v + bbv[ch - 8];
                }
            }
        }
    }
    __syncthreads();

    for (int e = tid; e < 512; e += 256) {
        int a = e >> 7, lp = e & 127;
        int p = p0 + lp;
        if (p < HW2) {
            float z1 = clsb[a][lp];
            float z2 = clsb[a + 4][lp];
            float mx = fmaxf(z1, z2);
            float e1 = expf(z1 - mx), e2 = expf(z2 - mx);
            scores[(size_t)b * NSC + a * HW2 + p] = e2 / (e1 + e2);
        }
    }
}

// ---------------- per-frame argmax + box decode ----------------
__global__ __launch_bounds__(256) void argmax_kernel(
    const float* __restrict__ scores, const float* __restrict__ deltas,
    const float* __restrict__ anchors, const float* __restrict__ im_info,
    float* __restrict__ out, float* __restrict__ boxesb, float* __restrict__ ssb)
{
    const int b = blockIdx.x, tid = threadIdx.x;
    const float* s = scores + (size_t)b * NSC;
    float best = -INFINITY;
    int bidx = 0;
    for (int i = tid; i < NSC; i += 256) {
        float v = s[i];
        if (v > best) { best = v; bidx = i; }
    }
    __shared__ float sv[256];
    __shared__ int   si[256];
    sv[tid] = best; si[tid] = bidx;
    __syncthreads();
    for (int stp = 128; stp > 0; stp >>= 1) {
        if (tid < stp) {
            float ov = sv[tid + stp]; int oi = si[tid + stp];
            if (ov > sv[tid] || (ov == sv[tid] && oi < si[tid])) { sv[tid] = ov; si[tid] = oi; }
        }
        __syncthreads();
    }
    if (tid == 0) {
        float ss = sv[0];
        int id = si[0];
        int kprime = id >> 2, aprime = id & 3;
        int hp = kprime / 38, wp = kprime - hp * 38;
        float im = im_info[0];
        float gx = (float)wp * 16.0f, gy = (float)hp * 16.0f;
#pragma unroll
        for (int j = 0; j < 4; ++j) {
            float shift = ((j & 1) == 0) ? gx : gy;
            float prop = anchors[aprime * 4 + j] + shift;
            float dlt = deltas[((size_t)b * 16 + (aprime * 4 + j)) * HW2 + kprime];
            float bx = (prop + dlt) * im;
            out[b * 9 + j]     = truncf(bx / im);
            out[b * 9 + 4 + j] = bx;
            boxesb[b * 4 + j]  = bx;
        }
        out[b * 9 + 8] = ss;
        ssb[b] = ss;
    }
}

// ---------------- proposal loss (nv = 1) ----------------
__global__ void loss_kernel(const int* __restrict__ central_pos,
                            const float* __restrict__ gt,
                            const float* __restrict__ boxesb,
                            const float* __restrict__ ssb,
                            float* __restrict__ out)
{
    if (threadIdx.x != 0 || blockIdx.x != 0) return;
    int idx = central_pos[0];
    bool valid = idx < NFRAMES;
    int idxc = min(max(idx, 0), NFRAMES - 1);
    float vb0 = boxesb[idxc * 4 + 0], vb1 = boxesb[idxc * 4 + 1];
    float vb2 = boxesb[idxc * 4 + 2], vb3 = boxesb[idxc * 4 + 3];
    float vs = ssb[idxc];
    float g0 = gt[0], g1 = gt[1], g2 = gt[2], g3 = gt[3];
    float xi1 = fmaxf(g0, vb0), yi1 = fmaxf(g1, vb1);
    float xi2 = fmaxf(g2, vb2), yi2 = fmaxf(g3, vb3);
    float inter = (xi2 - xi1) * (yi2 - yi1);
    float a1 = (g2 - g0) * (g3 - g1);
    float a2 = (vb2 - vb0) * (vb3 - vb1);
    float iou = inter / (a1 + a2 - inter);
    float lv = (iou > 0.7f) ? -logf(vs + 1e-5f) : -logf(1.0f - vs + 1e-5f);
    out[NFRAMES * 9] = valid ? lv : 0.0f;
}

// ---------------- host launcher ----------------
extern "C" void kernel_launch(void* const* d_in, const int* in_sizes, int n_in,
                              void* d_out, int out_size, void* d_ws, size_t ws_size,
                              hipStream_t stream) {
    const float* base_feat   = (const float*)d_in[0];
    const int*   central_pos = (const int*)d_in[1];
    const float* im_info     = (const float*)d_in[2];
    const float* gt_boxes    = (const float*)d_in[3];
    const float* W1 = (const float*)d_in[4];
    const float* b1 = (const float*)d_in[5];
    const float* Wc = (const float*)d_in[6];
    const float* bc = (const float*)d_in[7];
    const float* Wb = (const float*)d_in[8];
    const float* bb = (const float*)d_in[9];
    const float* anchors = (const float*)d_in[10];
    float* out = (float*)d_out;

    float* p = (float*)d_ws;
    unsigned int* xbuf = (unsigned int*)p; p += (size_t)CHUNK * COUT1 * PSTR;
    float* scores = p;  p += (size_t)NFRAMES * NSC;
    float* deltas = p;  p += (size_t)NFRAMES * 16 * HW2;
    _Float16* w1f = (_Float16*)p; p += 131072;   // 262144 halves
    _Float16* w2f = (_Float16*)p; p += 16384;    // 32768 halves
    float* boxesb = p;  p += NFRAMES * 4;
    float* ssb    = p;

    repack_w1f<<<512, 256, 0, stream>>>(W1, w1f);
    repack_w2f<<<64, 256, 0, stream>>>(Wc, Wb, w2f);

    for (int c = 0; c < NCHUNKS; ++c) {
        int f0 = c * CHUNK;
        conv1_mfma<<<dim3(12, CHUNK), 256, 0, stream>>>(base_feat, w1f, b1, xbuf, f0);
        stage2_mfma<<<dim3(12, CHUNK), 256, 0, stream>>>(xbuf, w2f, bc, bb, scores, deltas, f0);
    }
    argmax_kernel<<<NFRAMES, 256, 0, stream>>>(scores, deltas, anchors, im_info, out, boxesb, ssb);
    loss_kernel<<<1, 64, 0, stream>>>(central_pos, gt_boxes, boxesb, ssb, out);
}